// Round 1
// baseline (2492.801 us; speedup 1.0000x reference)
//
#include <hip/hip_runtime.h>
#include <hip/hip_bf16.h>

// Problem constants
#define CUT0 2000
#define CUT1 20000
#define CUT2 50000
#define BSZ  8192
#define HDIM 1024
#define N0MAX 18000   // CUT1-CUT0
#define N1MAX 30000   // CUT2-CUT1
#define HEADW 2002    // CUT0 + 2 tail cols

typedef __attribute__((ext_vector_type(8))) short bf16x8;
typedef __attribute__((ext_vector_type(4))) float f32x4;
typedef __attribute__((ext_vector_type(4))) unsigned short us4;
typedef __attribute__((ext_vector_type(4))) unsigned int u32x4;

__device__ __forceinline__ unsigned short f2bf(float x) {
    // round-to-nearest-even bf16
    unsigned u = __float_as_uint(x);
    unsigned r = u + 0x7fffu + ((u >> 16) & 1u);
    return (unsigned short)(r >> 16);
}

// ---------------------------------------------------------------------------
// Build idx0 (2000<=t<20000) and idx1 (t>=20000) in ascending order + counts.
// One block, 1024 threads, 8 contiguous targets each; Hillis-Steele scan.
// ---------------------------------------------------------------------------
__global__ __launch_bounds__(1024) void build_idx(const int* __restrict__ targets,
                                                  int* __restrict__ n0,
                                                  int* __restrict__ n1,
                                                  int* __restrict__ idx0,
                                                  int* __restrict__ idx1) {
    __shared__ int s0[1024], s1[1024];
    const int t = threadIdx.x;
    const int base = t * 8;
    int tg[8];
    int c0 = 0, c1 = 0;
#pragma unroll
    for (int i = 0; i < 8; ++i) {
        tg[i] = targets[base + i];
        c0 += (tg[i] >= CUT0 && tg[i] < CUT1) ? 1 : 0;
        c1 += (tg[i] >= CUT1) ? 1 : 0;
    }
    s0[t] = c0; s1[t] = c1;
    __syncthreads();
    for (int off = 1; off < 1024; off <<= 1) {
        int v0 = 0, v1 = 0;
        if (t >= off) { v0 = s0[t - off]; v1 = s1[t - off]; }
        __syncthreads();
        s0[t] += v0; s1[t] += v1;
        __syncthreads();
    }
    int p0 = s0[t] - c0, p1 = s1[t] - c1;   // exclusive prefix
#pragma unroll
    for (int i = 0; i < 8; ++i) {
        if (tg[i] >= CUT0 && tg[i] < CUT1)      idx0[p0++] = base + i;
        else if (tg[i] >= CUT1)                 idx1[p1++] = base + i;
    }
    if (t == 1023) { *n0 = s0[1023]; *n1 = s1[1023]; }
}

// ---------------------------------------------------------------------------
// head tail columns: out[:, 2000:2002] = hidden @ tail_vec_W^T + tail_vec_b
// One wave per row; fp32.
// ---------------------------------------------------------------------------
__global__ __launch_bounds__(256) void tail_head(const float* __restrict__ hidden,
                                                 const float* __restrict__ tailW,
                                                 const float* __restrict__ tailb,
                                                 float* __restrict__ out) {
    const int wave = threadIdx.x >> 6, lane = threadIdx.x & 63;
    const int row = blockIdx.x * 4 + wave;
    const float* h = hidden + (long long)row * HDIM;
    float s0 = 0.f, s1 = 0.f;
    for (int k = lane; k < HDIM; k += 64) {
        float x = h[k];
        s0 += x * tailW[k];
        s1 += x * tailW[HDIM + k];
    }
#pragma unroll
    for (int off = 32; off; off >>= 1) {
        s0 += __shfl_down(s0, off);
        s1 += __shfl_down(s1, off);
    }
    if (lane == 0) {
        out[(long long)row * HEADW + CUT0]     = s0 + tailb[0];
        out[(long long)row * HEADW + CUT0 + 1] = s1 + tailb[1];
    }
}

// ---------------------------------------------------------------------------
// Unified B^T GEMM: C[m,n] = sum_k A[m,k]*B[n,k] (+bias[n])
//   128x128 tile, BK=64, 4 waves (2x2), 64x64 per wave, 16x16x32 bf16 MFMA.
//   IN_BF16:  A,B are packed bf16 (ushort) else fp32 (converted in-register)
//   GATHER_A: A row index = idxA[m]
//   OUT_BF16: C packed bf16 row-major (ld=ldC) else fp32 at Cv + coff (+bias)
//   M from *Mdev if non-null (device count) else Mconst.
//   C fp32 offset = coff + (*coffM)*coffScale (for out1 after out0).
// ---------------------------------------------------------------------------
template<bool IN_BF16, bool GATHER_A, bool OUT_BF16, bool HAS_BIAS>
__global__ __launch_bounds__(256) void gemm_bt(
    const void* __restrict__ Av, const void* __restrict__ Bv,
    const int* __restrict__ idxA,
    const int* __restrict__ Mdev, int Mconst,
    int N, int K,
    const float* __restrict__ bias,
    void* __restrict__ Cv,
    long long coff, const int* __restrict__ coffM, long long coffScale,
    int ldC)
{
    const int M = Mdev ? *Mdev : Mconst;
    const int m0 = blockIdx.y * 128;
    const int n0 = blockIdx.x * 128;
    if (m0 >= M) return;

    // padded stride 72 bf16 (144 B): frag reads land 2-way on banks (free)
    __shared__ unsigned short As[128 * 72];
    __shared__ unsigned short Bs[128 * 72];

    const int tid  = threadIdx.x;
    const int wave = tid >> 6, lane = tid & 63;
    const int wr = wave >> 1, wc = wave & 1;
    const int lrow = lane & 15;   // fragment row (A/B operand row)
    const int quad = lane >> 4;   // 0..3

    f32x4 acc[4][4];
#pragma unroll
    for (int i = 0; i < 4; ++i)
#pragma unroll
        for (int j = 0; j < 4; ++j) acc[i][j] = (f32x4){0.f, 0.f, 0.f, 0.f};

    const int KT = K >> 6;   // BK = 64
    for (int kt = 0; kt < KT; ++kt) {
        if constexpr (IN_BF16) {
            const unsigned short* A  = (const unsigned short*)Av;
            const unsigned short* Bp = (const unsigned short*)Bv;
#pragma unroll
            for (int i = 0; i < 4; ++i) {
                int chunk = tid + i * 256;          // 0..1023, 8 bf16 each
                int row = chunk >> 3, kq = chunk & 7;
                int am = m0 + row;
                u32x4 v = {0u, 0u, 0u, 0u};
                if (am < M) {
                    long long r = GATHER_A ? (long long)idxA[am] : (long long)am;
                    v = *(const u32x4*)(A + r * (long long)K + (kt << 6) + (kq << 3));
                }
                *(u32x4*)&As[row * 72 + (kq << 3)] = v;
                int bn = n0 + row;
                u32x4 w = {0u, 0u, 0u, 0u};
                if (bn < N)
                    w = *(const u32x4*)(Bp + (long long)bn * K + (kt << 6) + (kq << 3));
                *(u32x4*)&Bs[row * 72 + (kq << 3)] = w;
            }
        } else {
            const float* A  = (const float*)Av;
            const float* Bp = (const float*)Bv;
#pragma unroll
            for (int i = 0; i < 8; ++i) {
                int chunk = tid + i * 256;          // 0..2047, 4 fp32 each
                int row = chunk >> 4, kq = chunk & 15;
                int am = m0 + row;
                f32x4 v = {0.f, 0.f, 0.f, 0.f};
                if (am < M) {
                    long long r = GATHER_A ? (long long)idxA[am] : (long long)am;
                    v = *(const f32x4*)(A + r * (long long)K + (kt << 6) + (kq << 2));
                }
                us4 pv = { f2bf(v[0]), f2bf(v[1]), f2bf(v[2]), f2bf(v[3]) };
                *(us4*)&As[row * 72 + (kq << 2)] = pv;
                int bn = n0 + row;
                f32x4 w = {0.f, 0.f, 0.f, 0.f};
                if (bn < N)
                    w = *(const f32x4*)(Bp + (long long)bn * K + (kt << 6) + (kq << 2));
                us4 pw = { f2bf(w[0]), f2bf(w[1]), f2bf(w[2]), f2bf(w[3]) };
                *(us4*)&Bs[row * 72 + (kq << 2)] = pw;
            }
        }
        __syncthreads();
#pragma unroll
        for (int ks = 0; ks < 2; ++ks) {
            bf16x8 a[4], b[4];
#pragma unroll
            for (int mi = 0; mi < 4; ++mi)
                a[mi] = *(const bf16x8*)&As[(wr * 64 + mi * 16 + lrow) * 72 + ks * 32 + quad * 8];
#pragma unroll
            for (int nj = 0; nj < 4; ++nj)
                b[nj] = *(const bf16x8*)&Bs[(wc * 64 + nj * 16 + lrow) * 72 + ks * 32 + quad * 8];
#pragma unroll
            for (int mi = 0; mi < 4; ++mi)
#pragma unroll
                for (int nj = 0; nj < 4; ++nj)
                    acc[mi][nj] = __builtin_amdgcn_mfma_f32_16x16x32_bf16(
                        a[mi], b[nj], acc[mi][nj], 0, 0, 0);
        }
        __syncthreads();
    }

    // epilogue: C/D layout col=lane&15, row=quad*4+reg  [m89/m91 verified]
    long long cbase = coff + (coffM ? (long long)(*coffM) * coffScale : 0ll);
#pragma unroll
    for (int mi = 0; mi < 4; ++mi) {
#pragma unroll
        for (int v = 0; v < 4; ++v) {
            int m = m0 + wr * 64 + mi * 16 + quad * 4 + v;
            if (m >= M) continue;
#pragma unroll
            for (int nj = 0; nj < 4; ++nj) {
                int n = n0 + wc * 64 + nj * 16 + lrow;
                if (n >= N) continue;
                float r = acc[mi][nj][v];
                if constexpr (OUT_BF16) {
                    ((unsigned short*)Cv)[(long long)m * ldC + n] = f2bf(r);
                } else {
                    if constexpr (HAS_BIAS) r += bias[n];
                    ((float*)Cv)[cbase + (long long)m * ldC + n] = r;
                }
            }
        }
    }
}

// ---------------------------------------------------------------------------
extern "C" void kernel_launch(void* const* d_in, const int* in_sizes, int n_in,
                              void* d_out, int out_size, void* d_ws, size_t ws_size,
                              hipStream_t stream) {
    (void)in_sizes; (void)n_in; (void)out_size; (void)ws_size;
    const float* hidden  = (const float*)d_in[0];
    const float* embed   = (const float*)d_in[1];
    const float* tailW   = (const float*)d_in[2];
    const float* tailb   = (const float*)d_in[3];
    const float* slbias  = (const float*)d_in[4];
    const float* bias0   = (const float*)d_in[5];
    const float* bias1   = (const float*)d_in[6];
    const float* down0   = (const float*)d_in[7];
    const float* down1   = (const float*)d_in[8];
    const int*   targets = (const int*)d_in[9];
    float* out = (float*)d_out;

    // workspace layout (~73 MB)
    char* ws = (char*)d_ws;
    int* n0p  = (int*)ws;
    int* n1p  = n0p + 1;
    int* idx0 = (int*)(ws + 256);
    int* idx1 = idx0 + BSZ;
    size_t off = 256 + 2 * (size_t)BSZ * 4;                 // 65792
    unsigned short* h0 = (unsigned short*)(ws + off); off += (size_t)BSZ * HDIM * 2;       // 16 MB
    unsigned short* h1 = (unsigned short*)(ws + off); off += (size_t)BSZ * 256 * 2;        // 4 MB
    unsigned short* e0 = (unsigned short*)(ws + off); off += (size_t)N0MAX * HDIM * 2;     // 36.9 MB
    unsigned short* e1 = (unsigned short*)(ws + off);                                      // 15.4 MB

    build_idx<<<1, 1024, 0, stream>>>(targets, n0p, n1p, idx0, idx1);

    // head[:, 0:2000] = hidden @ embed[0:2000]^T + shortlist_bias
    gemm_bt<false, false, false, true><<<dim3(16, 64), 256, 0, stream>>>(
        hidden, embed, nullptr, nullptr, BSZ, CUT0, HDIM,
        slbias, out, 0ll, nullptr, 0ll, HEADW);

    // head[:, 2000:2002]
    tail_head<<<BSZ / 4, 256, 0, stream>>>(hidden, tailW, tailb, out);

    // e0 = embed[2000:20000] @ down0^T  -> bf16
    gemm_bt<false, false, true, false><<<dim3(8, 141), 256, 0, stream>>>(
        embed + (long long)CUT0 * HDIM, down0, nullptr, nullptr, N0MAX, HDIM, HDIM,
        nullptr, e0, 0ll, nullptr, 0ll, HDIM);

    // e1 = embed[20000:50000] @ down1^T -> bf16
    gemm_bt<false, false, true, false><<<dim3(2, 235), 256, 0, stream>>>(
        embed + (long long)CUT1 * HDIM, down1, nullptr, nullptr, N1MAX, 256, HDIM,
        nullptr, e1, 0ll, nullptr, 0ll, 256);

    // h0 = hidden[idx0] @ down0^T -> bf16   (M = n0 on device)
    gemm_bt<false, true, true, false><<<dim3(8, 64), 256, 0, stream>>>(
        hidden, down0, idx0, n0p, 0, HDIM, HDIM,
        nullptr, h0, 0ll, nullptr, 0ll, HDIM);

    // h1 = hidden[idx1] @ down1^T -> bf16
    gemm_bt<false, true, true, false><<<dim3(2, 64), 256, 0, stream>>>(
        hidden, down1, idx1, n1p, 0, 256, HDIM,
        nullptr, h1, 0ll, nullptr, 0ll, 256);

    // out0 = h0 @ e0^T + bias0  (fp32 into d_out after head)
    gemm_bt<true, false, false, true><<<dim3(141, 64), 256, 0, stream>>>(
        h0, e0, nullptr, n0p, 0, N0MAX, HDIM,
        bias0, out, (long long)BSZ * HEADW, nullptr, 0ll, N0MAX);

    // out1 = h1 @ e1^T + bias1  (fp32 into d_out after out0; offset uses n0)
    gemm_bt<true, false, false, true><<<dim3(235, 64), 256, 0, stream>>>(
        h1, e1, nullptr, n1p, 0, N1MAX, 256,
        bias1, out, (long long)BSZ * HEADW, n0p, (long long)N0MAX, N1MAX);
}